// Round 18
// baseline (254.385 us; speedup 1.0000x reference)
//
#include <hip/hip_runtime.h>
#include <cstdint>
#include <cstddef>

#define B_    8
#define C_    256
#define DWH   13824      // 24*24*24
#define P3    27
#define COUT_ 256

// ---- workspace layout (float offsets) ----
#define OFF_XMEAN 0               // B*C*27 = 55296
#define OFF_WQT   55296           // 27*512 = 13824
#define OFF_WKT   69120           // 13824
#define OFF_BQ    82944           // 512
#define OFF_BK    83456           // 512
#define OFF_BETA  83968           // 256
#define OFF_ZT    90712           // B*8*7*256*4 = 458752
#define OFF_A     549464          // B*256*256 = 524288
#define OFF_MPH   1073752         // packed M hi (ushort) = 262144 float-slots
#define OFF_MPL   1335896         // 262144
// total = 1598040 floats = 6.39 MB

typedef __attribute__((ext_vector_type(8))) short bf16x8;
typedef __attribute__((ext_vector_type(4))) float f32x4;

__device__ __forceinline__ void split_bf16(float v, unsigned short& h, unsigned short& l) {
    unsigned u  = __float_as_uint(v);
    unsigned hu = u & 0xFFFF0000u;
    float r = v - __uint_as_float(hu);          // exact residual
    h = (unsigned short)(u >> 16);
    l = (unsigned short)(__float_as_uint(r) >> 16);
}

__device__ __forceinline__ unsigned rne2(float a, float b) {
    unsigned ua = __float_as_uint(a), ub = __float_as_uint(b);
    unsigned ra = (ua + 0x7FFFu + ((ua >> 16) & 1u)) >> 16;
    unsigned rb = (ub + 0x7FFFu + ((ub >> 16) & 1u)) >> 16;
    return ra | (rb << 16);
}

// ============ K1: fused {pool} U {combine} — round-11 verbatim ============
__global__ __launch_bounds__(256) void k_front(
    const float* __restrict__ x,
    const float* __restrict__ qk_w, const float* __restrict__ qk_b,
    const float* __restrict__ wq_w, const float* __restrict__ wq_b,
    const float* __restrict__ wk_w, const float* __restrict__ wk_b,
    float* __restrict__ xmean,
    float* __restrict__ WqT, float* __restrict__ WkT,
    float* __restrict__ bq, float* __restrict__ bk) {
    __shared__ float p0[576], p1[576], p2[576];
    __shared__ float part[216];
    if (blockIdx.x < 2048) {
        int bc = blockIdx.x;
        const float* xb = x + (size_t)bc * DWH;
        for (int t = threadIdx.x; t < 576; t += 256) {
            int g  = t >> 6;
            int s  = t & 63;
            int pd = g / 3, pw = g % 3;
            int d  = pd * 8 + (s >> 3);
            int w  = pw * 8 + (s & 7);
            const float4* r = (const float4*)(xb + ((size_t)d * 24 + w) * 24);
            float4 f0 = r[0], f1 = r[1], f2 = r[2], f3 = r[3], f4v = r[4], f5 = r[5];
            p0[t] = f0.x + f0.y + f0.z + f0.w + f1.x + f1.y + f1.z + f1.w;
            p1[t] = f2.x + f2.y + f2.z + f2.w + f3.x + f3.y + f3.z + f3.w;
            p2[t] = f4v.x + f4v.y + f4v.z + f4v.w + f5.x + f5.y + f5.z + f5.w;
        }
        __syncthreads();
        int tid = threadIdx.x;
        if (tid < 216) {
            int cell = tid >> 3, seg = tid & 7;
            int pd = cell / 9, pw = (cell / 3) % 3, ph = cell % 3;
            int g = pd * 3 + pw;
            const float* src = (ph == 0) ? p0 : (ph == 1 ? p1 : p2);
            float s = 0.f;
            #pragma unroll
            for (int i = 0; i < 8; ++i) s += src[g * 64 + seg * 8 + i];
            part[tid] = s;
        }
        __syncthreads();
        if (tid < 27) {
            float s = 0.f;
            #pragma unroll
            for (int i = 0; i < 8; ++i) s += part[tid * 8 + i];
            xmean[(size_t)bc * P3 + tid] = s * (1.0f / 512.0f);
        }
    } else {
        int t = (blockIdx.x - 2048) * 256 + threadIdx.x;
        if (t < 13824) {
            int j = t / 27, p = t % 27;
            float s = 0.f;
            for (int e = 0; e < 128; ++e) s += wq_w[j * 128 + e] * qk_w[e * 27 + p];
            WqT[p * 512 + j] = s;
        } else if (t < 27648) {
            int u = t - 13824, j = u / 27, p = u % 27;
            float s = 0.f;
            for (int e = 0; e < 128; ++e) s += wk_w[j * 128 + e] * qk_w[(128 + e) * 27 + p];
            WkT[p * 512 + j] = s;
        } else if (t < 28160) {
            int j = t - 27648;
            float s = wq_b[j];
            for (int e = 0; e < 128; ++e) s += wq_w[j * 128 + e] * qk_b[e];
            bq[j] = s;
        } else if (t < 28672) {
            int j = t - 28160;
            float s = wk_b[j];
            for (int e = 0; e < 128; ++e) s += wk_w[j * 128 + e] * qk_b[128 + e];
            bk[j] = s;
        }
    }
}

// ============ K2bc: G-in-LDS (bit-identical) + z~ transposed store ============
__global__ __launch_bounds__(256) void k_zG2(
    const float* __restrict__ WqT, const float* __restrict__ WkT,
    const float* __restrict__ bq, const float* __restrict__ bk,
    const float* __restrict__ xmean, float* __restrict__ ZT) {
    int h = blockIdx.x, b = blockIdx.y;
    int t = threadIdx.x;
    __shared__ float Wq[P3][65], Wk[P3][65];     // pad: bank=(p+w)%32
    __shared__ float bqs[64], bks[64];
    __shared__ float Gs[756], Us[P3], Vs[P3], Ds;
    for (int idx = t; idx < 1728; idx += 256) {
        int p = idx >> 6, w = idx & 63;
        Wq[p][w] = WqT[p * 512 + h * 64 + w];
        Wk[p][w] = WkT[p * 512 + h * 64 + w];
    }
    if (t < 64) { bqs[t] = bq[h * 64 + t]; bks[t] = bk[h * 64 + t]; }
    __syncthreads();
    for (int idx = t; idx < 811; idx += 256) {
        if (idx < 756) {
            int p = idx / 28, r = idx % 28;
            float s = 0.f;
            if (r < 27)
                for (int w = 0; w < 64; ++w) s += Wq[p][w] * Wk[r][w];
            Gs[p * 28 + r] = 0.125f * s;
        } else if (idx < 783) {
            int p = idx - 756;
            float s = 0.f;
            for (int w = 0; w < 64; ++w) s += Wq[p][w] * bks[w];
            Vs[p] = 0.125f * s;
        } else if (idx < 810) {
            int r = idx - 783;
            float s = 0.f;
            for (int w = 0; w < 64; ++w) s += Wk[r][w] * bqs[w];
            Us[r] = 0.125f * s;
        } else {
            float s = 0.f;
            for (int w = 0; w < 64; ++w) s += bqs[w] * bks[w];
            Ds = 0.125f * s;
        }
    }
    __syncthreads();
    int k = t;
    float xm[28];
    const float* xp = xmean + ((size_t)(b * C_) + k) * P3;
    #pragma unroll
    for (int r = 0; r < 27; ++r) xm[r] = xp[r];
    xm[27] = 0.f;
    float z[28];
    #pragma unroll
    for (int p = 0; p < 27; ++p) {
        float acc = Vs[p];
        #pragma unroll
        for (int r4 = 0; r4 < 7; ++r4) {
            float4 g = *(const float4*)&Gs[p * 28 + r4 * 4];
            acc += g.x * xm[r4 * 4] + g.y * xm[r4 * 4 + 1]
                 + g.z * xm[r4 * 4 + 2] + g.w * xm[r4 * 4 + 3];
        }
        z[p] = acc;
    }
    {
        float e = Ds;
        #pragma unroll
        for (int r = 0; r < 27; ++r) e += Us[r] * xm[r];
        z[27] = e;
    }
    float4* zt = (float4*)ZT;
    int bh = b * 8 + h;
    #pragma unroll
    for (int p4 = 0; p4 < 7; ++p4) {
        float4 v = {z[p4 * 4], z[p4 * 4 + 1], z[p4 * 4 + 2], z[p4 * 4 + 3]};
        zt[((size_t)(bh * 7 + p4)) * 256 + k] = v;
    }
}

// ============ K3: scores + softmax + head-combine — ss dbuf + scl hoist ============
__global__ __launch_bounds__(256) void k_attn(
    const float* __restrict__ xmean, const float* __restrict__ ZT,
    const float* __restrict__ fch_w, const float* __restrict__ fch_b,
    float* __restrict__ A, float* __restrict__ attn_out) {
    int b = blockIdx.y;
    int c0 = blockIdx.x * 4;
    int t = threadIdx.x;
    int lane = t & 63, wv = t >> 6;
    __shared__ float xsh[4 * 28];
    __shared__ float ss[2][4][256];            // 8 KB
    __shared__ float mx[4], scl[4];
    if (t < 112) {
        int i = t / 28, p = t % 28;
        xsh[t] = (p < 27) ? xmean[((size_t)(b * C_) + c0 + i) * P3 + p] : 1.0f;
    }
    __syncthreads();
    float4 xr[4][7];
    #pragma unroll
    for (int cl = 0; cl < 4; ++cl)
        #pragma unroll
        for (int p4 = 0; p4 < 7; ++p4)
            xr[cl][p4] = *(const float4*)&xsh[cl * 28 + p4 * 4];
    float areg[4] = {0.f, 0.f, 0.f, 0.f};
    const float4* zt = (const float4*)ZT;
    for (int h = 0; h < 8; ++h) {
        int buf = h & 1;
        int bh = b * 8 + h;
        float4 zk[7];
        #pragma unroll
        for (int p4 = 0; p4 < 7; ++p4)
            zk[p4] = zt[((size_t)(bh * 7 + p4)) * 256 + t];
        #pragma unroll
        for (int cl = 0; cl < 4; ++cl) {
            float dot = 0.f;
            #pragma unroll
            for (int p4 = 0; p4 < 7; ++p4) {
                float4 xv = xr[cl][p4];
                float4 zv = zk[p4];
                dot += xv.x * zv.x + xv.y * zv.y + xv.z * zv.z + xv.w * zv.w;
            }
            ss[buf][cl][t] = dot;
        }
        __syncthreads();                       // B1: ss[buf] visible
        {
            int cl = wv;
            float4 v = *(const float4*)&ss[buf][cl][lane * 4];
            float m = fmaxf(fmaxf(v.x, v.y), fmaxf(v.z, v.w));
            for (int off = 32; off; off >>= 1) m = fmaxf(m, __shfl_xor(m, off, 64));
            float s = expf(v.x - m) + expf(v.y - m) + expf(v.z - m) + expf(v.w - m);
            for (int off = 32; off; off >>= 1) s += __shfl_xor(s, off, 64);
            if (lane == 0) { mx[cl] = m; scl[cl] = fch_w[h] / s; }
        }
        __syncthreads();                       // B2: mx/scl visible
        #pragma unroll
        for (int cl = 0; cl < 4; ++cl)
            areg[cl] += expf(ss[buf][cl][t] - mx[cl]) * scl[cl];
        // no third barrier: next h writes the other ss buffer
    }
    float fb = fch_b[0];
    #pragma unroll
    for (int cl = 0; cl < 4; ++cl) {
        size_t idx = ((size_t)(b * C_) + c0 + cl) * C_ + t;
        A[idx] = areg[cl];
        attn_out[idx] = areg[cl] + fb;
    }
}

// ============ K4: M = conv_w@A + conv_w -> packed bf16 hi/lo + beta (4-row tiles) ====
__global__ __launch_bounds__(256) void k_M(
    const float* __restrict__ A, const float* __restrict__ conv_w,
    const float* __restrict__ fch_b, const float* __restrict__ conv_b,
    unsigned short* __restrict__ MpH, unsigned short* __restrict__ MpL,
    float* __restrict__ beta) {
    int b = blockIdx.y;
    int o0 = blockIdx.x * 4;
    int t = threadIdx.x;
    __shared__ float cw[4][256];
    #pragma unroll
    for (int r = 0; r < 4; ++r) cw[r][t] = conv_w[(o0 + r) * 256 + t];
    __syncthreads();
    float acc[4] = {0.f, 0.f, 0.f, 0.f};
    const float* Ab = A + (size_t)b * C_ * C_;
    for (int c = 0; c < 256; ++c) {
        float av = Ab[(size_t)c * 256 + t];
        #pragma unroll
        for (int r = 0; r < 4; ++r) acc[r] += cw[r][c] * av;
    }
    if (b == 0 && t < 4) {
        float s = 0.f;
        for (int c = 0; c < 256; ++c) s += cw[t][c];
        beta[o0 + t] = fch_b[0] * s + conv_b[o0 + t];
    }
    int ks = t >> 5, e = t & 7;
    int lanehi = ((t >> 3) & 3) << 4;
    size_t base = ((size_t)(b * 8 + ks) * 16 + (o0 >> 4)) * 64;
    int osub = (o0 & 12);
    #pragma unroll
    for (int r = 0; r < 4; ++r) {
        float mv = acc[r] + cw[r][t];
        unsigned short h, l;
        split_bf16(mv, h, l);
        size_t idx = (base + ((osub + r) | lanehi)) * 8 + e;
        MpH[idx] = h;
        MpL[idx] = l;
    }
}

// ============ K5: out = M@x + beta — 2-step X pipeline, 6 blocks/CU target ===========
// Live state ~80 VGPR (r14 measured 64 at 1-step); bounds(256,6) => 85-VGPR budget,
// 1536 co-resident blocks (grid 1728 -> 1.125 dispatch rounds vs 1.69 at 4/CU).
// NOT r15's mistake (32-VGPR budget vs 80 live); worst case mild remat.
__global__ __launch_bounds__(256, 6) void k_out_mfma(
    const bf16x8* __restrict__ MpH, const bf16x8* __restrict__ MpL,
    const float* __restrict__ x, const float* __restrict__ beta,
    float* __restrict__ out) {
    int b  = blockIdx.y;
    int n0 = blockIdx.x * 64;
    int t  = threadIdx.x;
    int lane = t & 63, wv = t >> 6;
    int l15  = lane & 15;
    int kseg = lane >> 4;

    __shared__ __align__(16) unsigned short Xs[2][64 * 32];   // 4 KB each

    f32x4 acc[4][4];
    #pragma unroll
    for (int m = 0; m < 4; ++m)
        #pragma unroll
        for (int nf = 0; nf < 4; ++nf) acc[m][nf] = (f32x4){0.f, 0.f, 0.f, 0.f};

    const float* xb = x + (size_t)b * 256 * DWH;
    const bf16x8* mh = MpH + (size_t)b * 8192;
    const bf16x8* ml = MpL + (size_t)b * 8192;

    int sn = t & 63;
    int sk = t >> 6;
    const float* xcol0 = xb + (size_t)(sk * 8) * DWH + n0 + sn;
    int soff = sn * 64 + ((sk * 16) ^ (((sn >> 1) & 3) << 4));

    float pend[2][8];                 // pend[(s+1)&1] holds x data for step s+1
    {
        float xr[8];
        #pragma unroll
        for (int j = 0; j < 8; ++j) xr[j] = xcol0[(size_t)j * DWH];
        uint4 v;
        v.x = rne2(xr[0], xr[1]); v.y = rne2(xr[2], xr[3]);
        v.z = rne2(xr[4], xr[5]); v.w = rne2(xr[6], xr[7]);
        *(uint4*)((char*)Xs[0] + soff) = v;
    }
    {
        const float* xc = xcol0 + (size_t)32 * DWH;
        #pragma unroll
        for (int j = 0; j < 8; ++j) pend[1][j] = xc[(size_t)j * DWH];
    }
    __syncthreads();

    #pragma unroll
    for (int s = 0; s < 8; ++s) {
        int cur = s & 1;
        if (s < 6) {
            const float* xc = xcol0 + (size_t)((s + 2) * 32) * DWH;
            #pragma unroll
            for (int j = 0; j < 8; ++j) pend[s & 1][j] = xc[(size_t)j * DWH];
        }
        bf16x8 Bf[4];
        #pragma unroll
        for (int nf = 0; nf < 4; ++nf) {
            int n = nf * 16 + l15;
            int off = n * 64 + ((kseg * 16) ^ (((n >> 1) & 3) << 4));
            Bf[nf] = *(const bf16x8*)((const char*)Xs[cur] + off);
        }
        #pragma unroll
        for (int m = 0; m < 4; ++m) {
            int idx = (s * 16 + wv * 4 + m) * 64 + lane;
            bf16x8 ah = mh[idx];
            bf16x8 al = ml[idx];
            #pragma unroll
            for (int nf = 0; nf < 4; ++nf) {
                f32x4 c = acc[m][nf];
                c = __builtin_amdgcn_mfma_f32_16x16x32_bf16(Bf[nf], al, c, 0, 0, 0);
                c = __builtin_amdgcn_mfma_f32_16x16x32_bf16(Bf[nf], ah, c, 0, 0, 0);
                acc[m][nf] = c;
            }
        }
        if (s < 7) {
            const float* pr = pend[(s + 1) & 1];
            uint4 v;
            v.x = rne2(pr[0], pr[1]); v.y = rne2(pr[2], pr[3]);
            v.z = rne2(pr[4], pr[5]); v.w = rne2(pr[6], pr[7]);
            *(uint4*)((char*)Xs[cur ^ 1] + soff) = v;
        }
        __syncthreads();
    }

    int r4 = (lane >> 4) * 4;
    int wo = wv * 64;
    #pragma unroll
    for (int m = 0; m < 4; ++m) {
        int o = wo + m * 16 + l15;
        float bet = beta[o];
        float* orow = out + ((size_t)(b * 256 + o)) * DWH + n0 + r4;
        #pragma unroll
        for (int nf = 0; nf < 4; ++nf) {
            f32x4 c = acc[m][nf];
            float4 v = {c[0] + bet, c[1] + bet, c[2] + bet, c[3] + bet};
            *(float4*)(orow + nf * 16) = v;
        }
    }
}

extern "C" void kernel_launch(void* const* d_in, const int* in_sizes, int n_in,
                              void* d_out, int out_size, void* d_ws, size_t ws_size,
                              hipStream_t stream) {
    const float* x      = (const float*)d_in[0];
    const float* qk_w   = (const float*)d_in[1];
    const float* qk_b   = (const float*)d_in[2];
    const float* wq_w   = (const float*)d_in[3];
    const float* wq_b   = (const float*)d_in[4];
    const float* wk_w   = (const float*)d_in[5];
    const float* wk_b   = (const float*)d_in[6];
    const float* fch_w  = (const float*)d_in[7];
    const float* fch_b  = (const float*)d_in[8];
    const float* conv_w = (const float*)d_in[9];
    const float* conv_b = (const float*)d_in[10];
    float* out = (float*)d_out;
    float* attn_out = out + (size_t)B_ * COUT_ * DWH;
    float* ws = (float*)d_ws;
    unsigned short* MpH = (unsigned short*)(ws + OFF_MPH);
    unsigned short* MpL = (unsigned short*)(ws + OFF_MPL);

    k_front<<<2160, 256, 0, stream>>>(x, qk_w, qk_b, wq_w, wq_b, wk_w, wk_b,
                                      ws + OFF_XMEAN, ws + OFF_WQT, ws + OFF_WKT,
                                      ws + OFF_BQ, ws + OFF_BK);
    k_zG2<<<dim3(8, B_), 256, 0, stream>>>(ws + OFF_WQT, ws + OFF_WKT,
                                           ws + OFF_BQ, ws + OFF_BK,
                                           ws + OFF_XMEAN, ws + OFF_ZT);
    k_attn<<<dim3(64, B_), 256, 0, stream>>>(ws + OFF_XMEAN, ws + OFF_ZT, fch_w, fch_b,
                                             ws + OFF_A, attn_out);
    k_M<<<dim3(64, B_), 256, 0, stream>>>(ws + OFF_A, conv_w, fch_b, conv_b,
                                          MpH, MpL, ws + OFF_BETA);
    k_out_mfma<<<dim3(216, B_), 256, 0, stream>>>((const bf16x8*)MpH, (const bf16x8*)MpL,
                                                  x, ws + OFF_BETA, out);
}

// Round 19
// 117.576 us; speedup vs baseline: 2.1636x; 2.1636x over previous
//
#include <hip/hip_runtime.h>
#include <cstdint>
#include <cstddef>

#define B_    8
#define C_    256
#define DWH   13824      // 24*24*24
#define P3    27
#define COUT_ 256

// ---- workspace layout (float offsets) ----
#define OFF_XMEAN 0               // B*C*27 = 55296
#define OFF_WQT   55296           // 27*512 = 13824
#define OFF_WKT   69120           // 13824
#define OFF_BQ    82944           // 512
#define OFF_BK    83456           // 512
#define OFF_BETA  83968           // 256
#define OFF_ZT    90712           // B*8*7*256*4 = 458752
#define OFF_A     549464          // B*256*256 = 524288
#define OFF_MPH   1073752         // packed M hi (ushort) = 262144 float-slots
#define OFF_MPL   1335896         // 262144
// total = 1598040 floats = 6.39 MB

typedef __attribute__((ext_vector_type(8))) short bf16x8;
typedef __attribute__((ext_vector_type(4))) float f32x4;

__device__ __forceinline__ void split_bf16(float v, unsigned short& h, unsigned short& l) {
    unsigned u  = __float_as_uint(v);
    unsigned hu = u & 0xFFFF0000u;
    float r = v - __uint_as_float(hu);          // exact residual
    h = (unsigned short)(u >> 16);
    l = (unsigned short)(__float_as_uint(r) >> 16);
}

__device__ __forceinline__ unsigned rne2(float a, float b) {
    unsigned ua = __float_as_uint(a), ub = __float_as_uint(b);
    unsigned ra = (ua + 0x7FFFu + ((ua >> 16) & 1u)) >> 16;
    unsigned rb = (ub + 0x7FFFu + ((ub >> 16) & 1u)) >> 16;
    return ra | (rb << 16);
}

// ============ K1: fused {pool} U {combine} ============
__global__ __launch_bounds__(256) void k_front(
    const float* __restrict__ x,
    const float* __restrict__ qk_w, const float* __restrict__ qk_b,
    const float* __restrict__ wq_w, const float* __restrict__ wq_b,
    const float* __restrict__ wk_w, const float* __restrict__ wk_b,
    float* __restrict__ xmean,
    float* __restrict__ WqT, float* __restrict__ WkT,
    float* __restrict__ bq, float* __restrict__ bk) {
    __shared__ float p0[576], p1[576], p2[576];
    __shared__ float part[216];
    if (blockIdx.x < 2048) {
        int bc = blockIdx.x;
        const float* xb = x + (size_t)bc * DWH;
        for (int t = threadIdx.x; t < 576; t += 256) {
            int g  = t >> 6;
            int s  = t & 63;
            int pd = g / 3, pw = g % 3;
            int d  = pd * 8 + (s >> 3);
            int w  = pw * 8 + (s & 7);
            const float4* r = (const float4*)(xb + ((size_t)d * 24 + w) * 24);
            float4 f0 = r[0], f1 = r[1], f2 = r[2], f3 = r[3], f4v = r[4], f5 = r[5];
            p0[t] = f0.x + f0.y + f0.z + f0.w + f1.x + f1.y + f1.z + f1.w;
            p1[t] = f2.x + f2.y + f2.z + f2.w + f3.x + f3.y + f3.z + f3.w;
            p2[t] = f4v.x + f4v.y + f4v.z + f4v.w + f5.x + f5.y + f5.z + f5.w;
        }
        __syncthreads();
        int tid = threadIdx.x;
        if (tid < 216) {
            int cell = tid >> 3, seg = tid & 7;
            int pd = cell / 9, pw = (cell / 3) % 3, ph = cell % 3;
            int g = pd * 3 + pw;
            const float* src = (ph == 0) ? p0 : (ph == 1 ? p1 : p2);
            float s = 0.f;
            #pragma unroll
            for (int i = 0; i < 8; ++i) s += src[g * 64 + seg * 8 + i];
            part[tid] = s;
        }
        __syncthreads();
        if (tid < 27) {
            float s = 0.f;
            #pragma unroll
            for (int i = 0; i < 8; ++i) s += part[tid * 8 + i];
            xmean[(size_t)bc * P3 + tid] = s * (1.0f / 512.0f);
        }
    } else {
        int t = (blockIdx.x - 2048) * 256 + threadIdx.x;
        if (t < 13824) {
            int j = t / 27, p = t % 27;
            float s = 0.f;
            for (int e = 0; e < 128; ++e) s += wq_w[j * 128 + e] * qk_w[e * 27 + p];
            WqT[p * 512 + j] = s;
        } else if (t < 27648) {
            int u = t - 13824, j = u / 27, p = u % 27;
            float s = 0.f;
            for (int e = 0; e < 128; ++e) s += wk_w[j * 128 + e] * qk_w[(128 + e) * 27 + p];
            WkT[p * 512 + j] = s;
        } else if (t < 28160) {
            int j = t - 27648;
            float s = wq_b[j];
            for (int e = 0; e < 128; ++e) s += wq_w[j * 128 + e] * qk_b[e];
            bq[j] = s;
        } else if (t < 28672) {
            int j = t - 28160;
            float s = wk_b[j];
            for (int e = 0; e < 128; ++e) s += wk_w[j * 128 + e] * qk_b[128 + e];
            bk[j] = s;
        }
    }
}

// ============ K2bc: G-in-LDS (bit-identical) + z~ transposed store ============
__global__ __launch_bounds__(256) void k_zG2(
    const float* __restrict__ WqT, const float* __restrict__ WkT,
    const float* __restrict__ bq, const float* __restrict__ bk,
    const float* __restrict__ xmean, float* __restrict__ ZT) {
    int h = blockIdx.x, b = blockIdx.y;
    int t = threadIdx.x;
    __shared__ float Wq[P3][65], Wk[P3][65];     // pad: bank=(p+w)%32
    __shared__ float bqs[64], bks[64];
    __shared__ float Gs[756], Us[P3], Vs[P3], Ds;
    for (int idx = t; idx < 1728; idx += 256) {
        int p = idx >> 6, w = idx & 63;
        Wq[p][w] = WqT[p * 512 + h * 64 + w];
        Wk[p][w] = WkT[p * 512 + h * 64 + w];
    }
    if (t < 64) { bqs[t] = bq[h * 64 + t]; bks[t] = bk[h * 64 + t]; }
    __syncthreads();
    for (int idx = t; idx < 811; idx += 256) {
        if (idx < 756) {
            int p = idx / 28, r = idx % 28;
            float s = 0.f;
            if (r < 27)
                for (int w = 0; w < 64; ++w) s += Wq[p][w] * Wk[r][w];
            Gs[p * 28 + r] = 0.125f * s;
        } else if (idx < 783) {
            int p = idx - 756;
            float s = 0.f;
            for (int w = 0; w < 64; ++w) s += Wq[p][w] * bks[w];
            Vs[p] = 0.125f * s;
        } else if (idx < 810) {
            int r = idx - 783;
            float s = 0.f;
            for (int w = 0; w < 64; ++w) s += Wk[r][w] * bqs[w];
            Us[r] = 0.125f * s;
        } else {
            float s = 0.f;
            for (int w = 0; w < 64; ++w) s += bqs[w] * bks[w];
            Ds = 0.125f * s;
        }
    }
    __syncthreads();
    int k = t;
    float xm[28];
    const float* xp = xmean + ((size_t)(b * C_) + k) * P3;
    #pragma unroll
    for (int r = 0; r < 27; ++r) xm[r] = xp[r];
    xm[27] = 0.f;
    float z[28];
    #pragma unroll
    for (int p = 0; p < 27; ++p) {
        float acc = Vs[p];
        #pragma unroll
        for (int r4 = 0; r4 < 7; ++r4) {
            float4 g = *(const float4*)&Gs[p * 28 + r4 * 4];
            acc += g.x * xm[r4 * 4] + g.y * xm[r4 * 4 + 1]
                 + g.z * xm[r4 * 4 + 2] + g.w * xm[r4 * 4 + 3];
        }
        z[p] = acc;
    }
    {
        float e = Ds;
        #pragma unroll
        for (int r = 0; r < 27; ++r) e += Us[r] * xm[r];
        z[27] = e;
    }
    float4* zt = (float4*)ZT;
    int bh = b * 8 + h;
    #pragma unroll
    for (int p4 = 0; p4 < 7; ++p4) {
        float4 v = {z[p4 * 4], z[p4 * 4 + 1], z[p4 * 4 + 2], z[p4 * 4 + 3]};
        zt[((size_t)(bh * 7 + p4)) * 256 + k] = v;
    }
}

// ============ K3: scores + softmax + head-combine — ss dbuf + scl hoist ============
__global__ __launch_bounds__(256) void k_attn(
    const float* __restrict__ xmean, const float* __restrict__ ZT,
    const float* __restrict__ fch_w, const float* __restrict__ fch_b,
    float* __restrict__ A, float* __restrict__ attn_out) {
    int b = blockIdx.y;
    int c0 = blockIdx.x * 4;
    int t = threadIdx.x;
    int lane = t & 63, wv = t >> 6;
    __shared__ float xsh[4 * 28];
    __shared__ float ss[2][4][256];            // 8 KB
    __shared__ float mx[4], scl[4];
    if (t < 112) {
        int i = t / 28, p = t % 28;
        xsh[t] = (p < 27) ? xmean[((size_t)(b * C_) + c0 + i) * P3 + p] : 1.0f;
    }
    __syncthreads();
    float4 xr[4][7];
    #pragma unroll
    for (int cl = 0; cl < 4; ++cl)
        #pragma unroll
        for (int p4 = 0; p4 < 7; ++p4)
            xr[cl][p4] = *(const float4*)&xsh[cl * 28 + p4 * 4];
    float areg[4] = {0.f, 0.f, 0.f, 0.f};
    const float4* zt = (const float4*)ZT;
    for (int h = 0; h < 8; ++h) {
        int buf = h & 1;
        int bh = b * 8 + h;
        float4 zk[7];
        #pragma unroll
        for (int p4 = 0; p4 < 7; ++p4)
            zk[p4] = zt[((size_t)(bh * 7 + p4)) * 256 + t];
        #pragma unroll
        for (int cl = 0; cl < 4; ++cl) {
            float dot = 0.f;
            #pragma unroll
            for (int p4 = 0; p4 < 7; ++p4) {
                float4 xv = xr[cl][p4];
                float4 zv = zk[p4];
                dot += xv.x * zv.x + xv.y * zv.y + xv.z * zv.z + xv.w * zv.w;
            }
            ss[buf][cl][t] = dot;
        }
        __syncthreads();                       // B1: ss[buf] visible
        {
            int cl = wv;
            float4 v = *(const float4*)&ss[buf][cl][lane * 4];
            float m = fmaxf(fmaxf(v.x, v.y), fmaxf(v.z, v.w));
            for (int off = 32; off; off >>= 1) m = fmaxf(m, __shfl_xor(m, off, 64));
            float s = expf(v.x - m) + expf(v.y - m) + expf(v.z - m) + expf(v.w - m);
            for (int off = 32; off; off >>= 1) s += __shfl_xor(s, off, 64);
            if (lane == 0) { mx[cl] = m; scl[cl] = fch_w[h] / s; }
        }
        __syncthreads();                       // B2: mx/scl visible
        #pragma unroll
        for (int cl = 0; cl < 4; ++cl)
            areg[cl] += expf(ss[buf][cl][t] - mx[cl]) * scl[cl];
        // no third barrier: next h writes the other ss buffer
    }
    float fb = fch_b[0];
    #pragma unroll
    for (int cl = 0; cl < 4; ++cl) {
        size_t idx = ((size_t)(b * C_) + c0 + cl) * C_ + t;
        A[idx] = areg[cl];
        attn_out[idx] = areg[cl] + fb;
    }
}

// ============ K4: M = conv_w@A + conv_w -> packed bf16 hi/lo + beta (4-row tiles) ====
__global__ __launch_bounds__(256) void k_M(
    const float* __restrict__ A, const float* __restrict__ conv_w,
    const float* __restrict__ fch_b, const float* __restrict__ conv_b,
    unsigned short* __restrict__ MpH, unsigned short* __restrict__ MpL,
    float* __restrict__ beta) {
    int b = blockIdx.y;
    int o0 = blockIdx.x * 4;
    int t = threadIdx.x;
    __shared__ float cw[4][256];
    #pragma unroll
    for (int r = 0; r < 4; ++r) cw[r][t] = conv_w[(o0 + r) * 256 + t];
    __syncthreads();
    float acc[4] = {0.f, 0.f, 0.f, 0.f};
    const float* Ab = A + (size_t)b * C_ * C_;
    for (int c = 0; c < 256; ++c) {
        float av = Ab[(size_t)c * 256 + t];
        #pragma unroll
        for (int r = 0; r < 4; ++r) acc[r] += cw[r][c] * av;
    }
    if (b == 0 && t < 4) {
        float s = 0.f;
        for (int c = 0; c < 256; ++c) s += cw[t][c];
        beta[o0 + t] = fch_b[0] * s + conv_b[o0 + t];
    }
    int ks = t >> 5, e = t & 7;
    int lanehi = ((t >> 3) & 3) << 4;
    size_t base = ((size_t)(b * 8 + ks) * 16 + (o0 >> 4)) * 64;
    int osub = (o0 & 12);
    #pragma unroll
    for (int r = 0; r < 4; ++r) {
        float mv = acc[r] + cw[r][t];
        unsigned short h, l;
        split_bf16(mv, h, l);
        size_t idx = (base + ((osub + r) | lanehi)) * 8 + e;
        MpH[idx] = h;
        MpL[idx] = l;
    }
}

// ============ K5: out = M@x + beta — 2-step X pipeline, bounds(256,4) ONLY ===========
// Occupancy ledger: bounds(256,4) -> VGPR 64-80, no spill, 56us (r17 best).
// bounds(256,6) -> VGPR 40, full spill, 190us (r18). bounds(256,8) -> VGPR 32,
// full spill, 310us (r15). Do not raise past 4.
__global__ __launch_bounds__(256, 4) void k_out_mfma(
    const bf16x8* __restrict__ MpH, const bf16x8* __restrict__ MpL,
    const float* __restrict__ x, const float* __restrict__ beta,
    float* __restrict__ out) {
    int b  = blockIdx.y;
    int n0 = blockIdx.x * 64;
    int t  = threadIdx.x;
    int lane = t & 63, wv = t >> 6;
    int l15  = lane & 15;
    int kseg = lane >> 4;

    __shared__ __align__(16) unsigned short Xs[2][64 * 32];   // 4 KB each

    f32x4 acc[4][4];
    #pragma unroll
    for (int m = 0; m < 4; ++m)
        #pragma unroll
        for (int nf = 0; nf < 4; ++nf) acc[m][nf] = (f32x4){0.f, 0.f, 0.f, 0.f};

    const float* xb = x + (size_t)b * 256 * DWH;
    const bf16x8* mh = MpH + (size_t)b * 8192;
    const bf16x8* ml = MpL + (size_t)b * 8192;

    int sn = t & 63;
    int sk = t >> 6;
    const float* xcol0 = xb + (size_t)(sk * 8) * DWH + n0 + sn;
    int soff = sn * 64 + ((sk * 16) ^ (((sn >> 1) & 3) << 4));

    float pend[2][8];                 // pend[(s+1)&1] holds x data for step s+1
    {
        float xr[8];
        #pragma unroll
        for (int j = 0; j < 8; ++j) xr[j] = xcol0[(size_t)j * DWH];
        uint4 v;
        v.x = rne2(xr[0], xr[1]); v.y = rne2(xr[2], xr[3]);
        v.z = rne2(xr[4], xr[5]); v.w = rne2(xr[6], xr[7]);
        *(uint4*)((char*)Xs[0] + soff) = v;
    }
    {
        const float* xc = xcol0 + (size_t)32 * DWH;
        #pragma unroll
        for (int j = 0; j < 8; ++j) pend[1][j] = xc[(size_t)j * DWH];
    }
    __syncthreads();

    #pragma unroll
    for (int s = 0; s < 8; ++s) {
        int cur = s & 1;
        if (s < 6) {
            const float* xc = xcol0 + (size_t)((s + 2) * 32) * DWH;
            #pragma unroll
            for (int j = 0; j < 8; ++j) pend[s & 1][j] = xc[(size_t)j * DWH];
        }
        bf16x8 Bf[4];
        #pragma unroll
        for (int nf = 0; nf < 4; ++nf) {
            int n = nf * 16 + l15;
            int off = n * 64 + ((kseg * 16) ^ (((n >> 1) & 3) << 4));
            Bf[nf] = *(const bf16x8*)((const char*)Xs[cur] + off);
        }
        #pragma unroll
        for (int m = 0; m < 4; ++m) {
            int idx = (s * 16 + wv * 4 + m) * 64 + lane;
            bf16x8 ah = mh[idx];
            bf16x8 al = ml[idx];
            #pragma unroll
            for (int nf = 0; nf < 4; ++nf) {
                f32x4 c = acc[m][nf];
                c = __builtin_amdgcn_mfma_f32_16x16x32_bf16(Bf[nf], al, c, 0, 0, 0);
                c = __builtin_amdgcn_mfma_f32_16x16x32_bf16(Bf[nf], ah, c, 0, 0, 0);
                acc[m][nf] = c;
            }
        }
        if (s < 7) {
            const float* pr = pend[(s + 1) & 1];
            uint4 v;
            v.x = rne2(pr[0], pr[1]); v.y = rne2(pr[2], pr[3]);
            v.z = rne2(pr[4], pr[5]); v.w = rne2(pr[6], pr[7]);
            *(uint4*)((char*)Xs[cur ^ 1] + soff) = v;
        }
        __syncthreads();
    }

    int r4 = (lane >> 4) * 4;
    int wo = wv * 64;
    #pragma unroll
    for (int m = 0; m < 4; ++m) {
        int o = wo + m * 16 + l15;
        float bet = beta[o];
        float* orow = out + ((size_t)(b * 256 + o)) * DWH + n0 + r4;
        #pragma unroll
        for (int nf = 0; nf < 4; ++nf) {
            f32x4 c = acc[m][nf];
            float4 v = {c[0] + bet, c[1] + bet, c[2] + bet, c[3] + bet};
            *(float4*)(orow + nf * 16) = v;
        }
    }
}

extern "C" void kernel_launch(void* const* d_in, const int* in_sizes, int n_in,
                              void* d_out, int out_size, void* d_ws, size_t ws_size,
                              hipStream_t stream) {
    const float* x      = (const float*)d_in[0];
    const float* qk_w   = (const float*)d_in[1];
    const float* qk_b   = (const float*)d_in[2];
    const float* wq_w   = (const float*)d_in[3];
    const float* wq_b   = (const float*)d_in[4];
    const float* wk_w   = (const float*)d_in[5];
    const float* wk_b   = (const float*)d_in[6];
    const float* fch_w  = (const float*)d_in[7];
    const float* fch_b  = (const float*)d_in[8];
    const float* conv_w = (const float*)d_in[9];
    const float* conv_b = (const float*)d_in[10];
    float* out = (float*)d_out;
    float* attn_out = out + (size_t)B_ * COUT_ * DWH;
    float* ws = (float*)d_ws;
    unsigned short* MpH = (unsigned short*)(ws + OFF_MPH);
    unsigned short* MpL = (unsigned short*)(ws + OFF_MPL);

    k_front<<<2160, 256, 0, stream>>>(x, qk_w, qk_b, wq_w, wq_b, wk_w, wk_b,
                                      ws + OFF_XMEAN, ws + OFF_WQT, ws + OFF_WKT,
                                      ws + OFF_BQ, ws + OFF_BK);
    k_zG2<<<dim3(8, B_), 256, 0, stream>>>(ws + OFF_WQT, ws + OFF_WKT,
                                           ws + OFF_BQ, ws + OFF_BK,
                                           ws + OFF_XMEAN, ws + OFF_ZT);
    k_attn<<<dim3(64, B_), 256, 0, stream>>>(ws + OFF_XMEAN, ws + OFF_ZT, fch_w, fch_b,
                                             ws + OFF_A, attn_out);
    k_M<<<dim3(64, B_), 256, 0, stream>>>(ws + OFF_A, conv_w, fch_b, conv_b,
                                          MpH, MpL, ws + OFF_BETA);
    k_out_mfma<<<dim3(216, B_), 256, 0, stream>>>((const bf16x8*)MpH, (const bf16x8*)MpL,
                                                  x, ws + OFF_BETA, out);
}